// Round 9
// baseline (101.052 us; speedup 1.0000x reference)
//
#include <hip/hip_runtime.h>
#include <math.h>

#define TSTEPS 48
#define FEAT 60
#define BATCH 128
#define BLOCK 256
#define TWO_PI_F 6.2831853071795864769f

// Recurrence = 5-qubit (32-amp) sim; visible outputs are a pure parallel
// function of x (CRX only couples hidden qubits; visible stays product).
// R9 layout: 2 amps/thread x 4 lane bits (lanes 16-63 mirror lanes 0-15).
//   q0 = register index, q1 = lane bit3, q2 = bit2, q3 = bit1, q4 = bit0.
// L1 (1q trios + CRX chain) folds ENTIRELY into the embedding product:
//   amp[r] = e0[r] * E1^(r)[l3] * E2^(l3)[l2] * E3^(l2)[l1] * E4^(l1)[l0]
// (diagonal controls select which per-qubit 2-vector row each lane uses).
// L2: q0 gate = in-register 2x2; q1..q4 gates + CRX chain = DPP-only
// cross-lane ops (masks 8,4,2,1). NO LDS, NO barriers, NO ds-pipe shuffles
// anywhere in the recurrence.

struct Cf { float r, i; };
__device__ __forceinline__ Cf cmul(Cf a, Cf b){ return {a.r*b.r - a.i*b.i, a.r*b.i + a.i*b.r}; }
__device__ __forceinline__ void mm2(const Cf A[4], const Cf B[4], Cf D[4]) {
  D[0] = {A[0].r*B[0].r - A[0].i*B[0].i + A[1].r*B[2].r - A[1].i*B[2].i,
          A[0].r*B[0].i + A[0].i*B[0].r + A[1].r*B[2].i + A[1].i*B[2].r};
  D[1] = {A[0].r*B[1].r - A[0].i*B[1].i + A[1].r*B[3].r - A[1].i*B[3].i,
          A[0].r*B[1].i + A[0].i*B[1].r + A[1].r*B[3].i + A[1].i*B[3].r};
  D[2] = {A[2].r*B[0].r - A[2].i*B[0].i + A[3].r*B[2].r - A[3].i*B[2].i,
          A[2].r*B[0].i + A[2].i*B[0].r + A[3].r*B[2].i + A[3].i*B[2].r};
  D[3] = {A[2].r*B[1].r - A[2].i*B[1].i + A[3].r*B[3].r - A[3].i*B[3].i,
          A[2].r*B[1].i + A[2].i*B[1].r + A[3].r*B[3].i + A[3].i*B[3].r};
}

// fused U = RZ * RY * RX from 3 consecutive params
__device__ __forceinline__ void fusedU(const float* p, Cf U[4]) {
  float cx = cosf(0.5f*p[0]), sxn = sinf(0.5f*p[0]);
  float cy = cosf(0.5f*p[1]), syn = sinf(0.5f*p[1]);
  float cz = cosf(0.5f*p[2]), szn = sinf(0.5f*p[2]);
  Cf RX[4] = {{cx,0.f},{0.f,-sxn},{0.f,-sxn},{cx,0.f}};
  Cf RY[4] = {{cy,0.f},{-syn,0.f},{syn,0.f},{cy,0.f}};
  Cf RZ[4] = {{cz,-szn},{0.f,0.f},{0.f,0.f},{cz,szn}};
  Cf M[4];
  mm2(RY, RX, M);
  mm2(RZ, M, U);
}

template<int CTRL>
__device__ __forceinline__ float dppf(float v) {
  return __int_as_float(__builtin_amdgcn_mov_dpp(__float_as_int(v), CTRL, 0xF, 0xF, true));
}

// xor-lane exchange, ALL DPP: 1,2 quad_perm; 4 = half_mirror(xor7)∘quad_rev(xor3);
// 8 = row_ror:8 (within 16-lane row == xor8)
template<int M>
__device__ __forceinline__ float sx(float v) {
  if constexpr (M == 1)      return dppf<0xB1>(v);
  else if constexpr (M == 2) return dppf<0x4E>(v);
  else if constexpr (M == 4) return dppf<0x141>(dppf<0x1B>(v));
  else                       return dppf<0x128>(v);   // M == 8
}

// 1q gate on lane-bit MASK; m = this lane's row (m.xy * a + m.zw * partner)
template<int MASK>
__device__ __forceinline__ void lgate(float2& a, float4 m) {
  float px = sx<MASK>(a.x), py = sx<MASK>(a.y);
  float ax = a.x, ay = a.y;
  a.x = m.x*ax - m.y*ay + m.z*px - m.w*py;
  a.y = m.x*ay + m.y*ax + m.z*py + m.w*px;
}

// full 2x2 on the in-thread register pair (q0)
__device__ __forceinline__ void rgate(float2& A, float2& B, float4 r0, float4 r1) {
  float2 A0 = A, B0 = B;
  A.x = r0.x*A0.x - r0.y*A0.y + r0.z*B0.x - r0.w*B0.y;
  A.y = r0.x*A0.y + r0.y*A0.x + r0.z*B0.y + r0.w*B0.x;
  B.x = r1.x*A0.x - r1.y*A0.y + r1.z*B0.x - r1.w*B0.y;
  B.y = r1.x*A0.y + r1.y*A0.x + r1.z*B0.y + r1.w*B0.x;
}

// (controlled-)RX across lane-bit MASK, per-lane blended c,s: a' = c*a - i*s*partner
template<int MASK>
__device__ __forceinline__ void rxs(float2& a, float c, float s) {
  float px = sx<MASK>(a.x), py = sx<MASK>(a.y);
  float ax = a.x, ay = a.y;
  a.x = c*ax + s*py;
  a.y = c*ay - s*px;
}

__device__ __forceinline__ float4 rowsel(const Cf U[4], int bit) {
  return bit ? make_float4(U[3].r, U[3].i, U[2].r, U[2].i)
             : make_float4(U[0].r, U[0].i, U[1].r, U[1].i);
}

__global__ __launch_bounds__(BLOCK)
void qrnn_kernel(const float* __restrict__ x, const float* __restrict__ hin,
                 const float* __restrict__ params, float* __restrict__ out) {
  const int b    = blockIdx.x;
  const int tid  = threadIdx.x;
  const int lane = tid & 63;
  const int w    = tid >> 6;

  if (w == 0) {
    // ================= hidden recurrence (single wave, all-DPP) ============
    const int l3 = (lane>>3)&1, l2 = (lane>>2)&1, l1 = (lane>>1)&1, l0 = lane&1;

    // layer-1 fused 1q matrices for hidden qubits (lane-uniform, full 2x2)
    Cf u1q[5][4];
    #pragma unroll
    for (int q = 0; q < 5; ++q) fusedU(params + 3*q, u1q[q]);
    // L1 CRX constants: (q0,q1) full; (q1,q2),(q2,q3),(q3,q4) blended by ctrl bit
    float c1f, s1f, cB2, sB2, cB3, sB3, cB4, sB4;
    { float t0 = params[15]; c1f = cosf(0.5f*t0); s1f = sinf(0.5f*t0); }
    { float t1 = params[16]; cB2 = l3 ? cosf(0.5f*t1) : 1.f; sB2 = l3 ? sinf(0.5f*t1) : 0.f; }
    { float t2 = params[17]; cB3 = l2 ? cosf(0.5f*t2) : 1.f; sB3 = l2 ? sinf(0.5f*t2) : 0.f; }
    { float t3 = params[18]; cB4 = l1 ? cosf(0.5f*t3) : 1.f; sB4 = l1 ? sinf(0.5f*t3) : 0.f; }
    // layer-2 fused 1q gates: q0 full (register gate), q1..q4 row-selected
    float4 Mq0r0, Mq0r1, r2q1, r2q2, r2q3, r2q4;
    { Cf U[4]; fusedU(params + 37, U);
      Mq0r0 = make_float4(U[0].r, U[0].i, U[1].r, U[1].i);
      Mq0r1 = make_float4(U[2].r, U[2].i, U[3].r, U[3].i); }
    { Cf U[4]; fusedU(params + 40, U); r2q1 = rowsel(U, l3); }
    { Cf U[4]; fusedU(params + 43, U); r2q2 = rowsel(U, l2); }
    { Cf U[4]; fusedU(params + 46, U); r2q3 = rowsel(U, l1); }
    { Cf U[4]; fusedU(params + 49, U); r2q4 = rowsel(U, l0); }
    // layer-2 CRX constants
    float c2f, s2f, cC2, sC2, cC3, sC3, cC4, sC4;
    { float t0 = params[52]; c2f = cosf(0.5f*t0); s2f = sinf(0.5f*t0); }
    { float t1 = params[53]; cC2 = l3 ? cosf(0.5f*t1) : 1.f; sC2 = l3 ? sinf(0.5f*t1) : 0.f; }
    { float t2 = params[54]; cC3 = l2 ? cosf(0.5f*t2) : 1.f; sC3 = l2 ? sinf(0.5f*t2) : 0.f; }
    { float t3 = params[55]; cC4 = l1 ? cosf(0.5f*t3) : 1.f; sC4 = l1 ? sinf(0.5f*t3) : 0.f; }

    // hidden state stored as HALF-angles (trig consumes h directly)
    const float* hp = hin + b*5;
    float h0 = 0.5f*hp[0], h1 = 0.5f*hp[1], h2 = 0.5f*hp[2],
          h3 = 0.5f*hp[3], h4 = 0.5f*hp[4];

    #pragma unroll 1
    for (int t = 0; t < TSTEPS; ++t) {
      float cc0 = __cosf(h0), ss0 = __sinf(h0);
      float cc1 = __cosf(h1), ss1 = __sinf(h1);
      float cc2 = __cosf(h2), ss2 = __sinf(h2);
      float cc3 = __cosf(h3), ss3 = __sinf(h3);
      float cc4 = __cosf(h4), ss4 = __sinf(h4);
      // e_q = U1q * (cos, -i sin): both components
      Cf e0a{u1q[0][0].r*cc0 + u1q[0][1].i*ss0, u1q[0][0].i*cc0 - u1q[0][1].r*ss0};
      Cf e0b{u1q[0][2].r*cc0 + u1q[0][3].i*ss0, u1q[0][2].i*cc0 - u1q[0][3].r*ss0};
      Cf e1a{u1q[1][0].r*cc1 + u1q[1][1].i*ss1, u1q[1][0].i*cc1 - u1q[1][1].r*ss1};
      Cf e1b{u1q[1][2].r*cc1 + u1q[1][3].i*ss1, u1q[1][2].i*cc1 - u1q[1][3].r*ss1};
      Cf e2a{u1q[2][0].r*cc2 + u1q[2][1].i*ss2, u1q[2][0].i*cc2 - u1q[2][1].r*ss2};
      Cf e2b{u1q[2][2].r*cc2 + u1q[2][3].i*ss2, u1q[2][2].i*cc2 - u1q[2][3].r*ss2};
      Cf e3a{u1q[3][0].r*cc3 + u1q[3][1].i*ss3, u1q[3][0].i*cc3 - u1q[3][1].r*ss3};
      Cf e3b{u1q[3][2].r*cc3 + u1q[3][3].i*ss3, u1q[3][2].i*cc3 - u1q[3][3].r*ss3};
      Cf e4a{u1q[4][0].r*cc4 + u1q[4][1].i*ss4, u1q[4][0].i*cc4 - u1q[4][1].r*ss4};
      Cf e4b{u1q[4][2].r*cc4 + u1q[4][3].i*ss4, u1q[4][2].i*cc4 - u1q[4][3].r*ss4};

      // per-lane row selects + L1-CRX folds
      Cf E1s = l3 ? e1b : e1a, E1x = l3 ? e1a : e1b;
      Cf G0  = E1s;                                            // r=0 branch
      Cf G1  {c1f*E1s.r + s1f*E1x.i, c1f*E1s.i - s1f*E1x.r};   // r=1: RX1 fold
      Cf E2s = l2 ? e2b : e2a, E2x = l2 ? e2a : e2b;
      Cf E2  {cB2*E2s.r + sB2*E2x.i, cB2*E2s.i - sB2*E2x.r};
      Cf E3s = l1 ? e3b : e3a, E3x = l1 ? e3a : e3b;
      Cf E3  {cB3*E3s.r + sB3*E3x.i, cB3*E3s.i - sB3*E3x.r};
      Cf E4s = l0 ? e4b : e4a, E4x = l0 ? e4a : e4b;
      Cf E4  {cB4*E4s.r + sB4*E4x.i, cB4*E4s.i - sB4*E4x.r};

      Cf C  = cmul(E2, cmul(E3, E4));
      Cf A0 = cmul(cmul(e0a, G0), C);
      Cf A1 = cmul(cmul(e0b, G1), C);
      float2 a0{A0.r, A0.i}, a1{A1.r, A1.i};

      // layer 2: 1q gates (q0 in-register, q1..q4 DPP)
      rgate(a0, a1, Mq0r0, Mq0r1);
      lgate<8>(a0, r2q1); lgate<8>(a1, r2q1);
      lgate<4>(a0, r2q2); lgate<4>(a1, r2q2);
      lgate<2>(a0, r2q3); lgate<2>(a1, r2q3);
      lgate<1>(a0, r2q4); lgate<1>(a1, r2q4);
      // layer 2 CRX chain: (q0,q1) hits a1 only; rest blended
      rxs<8>(a1, c2f, s2f);
      rxs<4>(a0, cC2, sC2); rxs<4>(a1, cC2, sC2);
      rxs<2>(a0, cC3, sC3); rxs<2>(a1, cC3, sC3);
      rxs<1>(a0, cC4, sC4); rxs<1>(a1, cC4, sC4);

      // measurement, scaled by 0.5 (next step consumes half-angles)
      float p0 = (0.5f*a0.x)*a0.x + (0.5f*a0.y)*a0.y;
      float p1 = (0.5f*a1.x)*a1.x + (0.5f*a1.y)*a1.y;
      float S = p0 + p1, D = p0 - p1;
      float T1, T2, T4, T8;
      { float xx = sx<1>(S); T1 = (lane&1) ? xx-S : S-xx; S += xx; D += sx<1>(D); }
      { float xx = sx<2>(S); T2 = (lane&2) ? xx-S : S-xx; S += xx; D += sx<2>(D);
        T1 += sx<2>(T1); }
      { float xx = sx<4>(S); T4 = (lane&4) ? xx-S : S-xx; S += xx; D += sx<4>(D);
        T1 += sx<4>(T1); T2 += sx<4>(T2); }
      { float xx = sx<8>(S); T8 = (lane&8) ? xx-S : S-xx; S += xx; D += sx<8>(D);
        T1 += sx<8>(T1); T2 += sx<8>(T2); T4 += sx<8>(T4); }
      h0 = D; h1 = T8; h2 = T4; h3 = T2; h4 = T1;
    }
    if (lane < 5) {
      float hv = (lane==0) ? h0 : (lane==1) ? h1 : (lane==2) ? h2
               : (lane==3) ? h3 : h4;
      out[BATCH*TSTEPS*6 + b*5 + lane] = 2.f*hv;    // un-halve
    }
  } else if (w == 1) {
    // ================= visible outputs (no recurrence) =====================
    const int t = lane;
    if (t < TSTEPS) {
      const float* xp = x + (size_t)b*(TSTEPS*FEAT) + t*FEAT;
      float pooled[6];
      #pragma unroll
      for (int k = 0; k < 6; ++k) {
        float s = 0.f;
        #pragma unroll
        for (int f = 0; f < 10; ++f) s += xp[k*10 + f];
        pooled[k] = s * 0.1f;
      }
      float mn = pooled[0], mx = pooled[0];
      #pragma unroll
      for (int v = 1; v < 6; ++v) {
        mn = fminf(mn, pooled[v]); mx = fmaxf(mx, pooled[v]);
      }
      float* op = out + (size_t)b*(TSTEPS*6) + t*6;
      #pragma unroll
      for (int k = 0; k < 6; ++k) {
        Cf U1[4], U2[4], W[4];
        fusedU(params + 19 + 3*k, U1);       // layer 1, visible qubit k
        fusedU(params + 56 + 3*k, U2);       // layer 2, visible qubit k
        mm2(U2, U1, W);                      // W = U2*U1
        float ang = TWO_PI_F * (pooled[k] - mn) / (mx - mn + 1e-8f);
        float ch = __cosf(0.5f*ang), sh = __sinf(0.5f*ang);
        float v0r = W[0].r*ch + W[1].i*sh, v0i = W[0].i*ch - W[1].r*sh;
        float v1r = W[2].r*ch + W[3].i*sh, v1i = W[2].i*ch - W[3].r*sh;
        op[k] = (v0r*v0r + v0i*v0i) - (v1r*v1r + v1i*v1i);
      }
    }
  }
}

extern "C" void kernel_launch(void* const* d_in, const int* in_sizes, int n_in,
                              void* d_out, int out_size, void* d_ws, size_t ws_size,
                              hipStream_t stream) {
  const float* x      = (const float*)d_in[0];
  const float* hidden = (const float*)d_in[1];
  const float* params = (const float*)d_in[2];
  float* out          = (float*)d_out;
  qrnn_kernel<<<dim3(BATCH), dim3(BLOCK), 0, stream>>>(x, hidden, params, out);
}

// Round 10
// 100.592 us; speedup vs baseline: 1.0046x; 1.0046x over previous
//
#include <hip/hip_runtime.h>
#include <math.h>

#define TSTEPS 48
#define FEAT 60
#define BATCH 128
#define BLOCK 256
#define TWO_PI_F 6.2831853071795864769f

// Recurrence = 5-qubit (32-amp) sim (CRX only couples hidden qubits; visible
// qubits stay product -> outputs are a pure parallel function of x).
// Layout: 2 amps/thread x 4 lane bits (lanes 16..63 mirror lanes 0..15).
//   q0 = register index, q1 = l3, q2 = l2, q3 = l1, q4 = l0.
// L1 (1q trios + CRX chain) folds into the embedding product (R9, verified).
// R10: L2 collapses to THREE passes:
//   rgate(U0 on reg)
//   pass A = CRX12 · (r? RX1 on l3 : I) · (U1 (x) U2)   -- fixed 4x4 on (l3,l2)
//   pass B = CRX34 · (l2? RX3 on l1 : I) · (U3 (x) U4)  -- fixed 4x4 on (l1,l0)
// Per-lane 4-term row coefficients precomputed at setup. All exchanges DPP.

struct Cf { float r, i; };
__device__ __forceinline__ Cf cmul(Cf a, Cf b){ return {a.r*b.r - a.i*b.i, a.r*b.i + a.i*b.r}; }
__device__ __forceinline__ Cf cadd(Cf a, Cf b){ return {a.r+b.r, a.i+b.i}; }
__device__ __forceinline__ void mm2(const Cf A[4], const Cf B[4], Cf D[4]) {
  D[0] = cadd(cmul(A[0],B[0]), cmul(A[1],B[2]));
  D[1] = cadd(cmul(A[0],B[1]), cmul(A[1],B[3]));
  D[2] = cadd(cmul(A[2],B[0]), cmul(A[3],B[2]));
  D[3] = cadd(cmul(A[2],B[1]), cmul(A[3],B[3]));
}

// fused U = RZ * RY * RX from 3 consecutive params
__device__ __forceinline__ void fusedU(const float* p, Cf U[4]) {
  float cx = cosf(0.5f*p[0]), sxn = sinf(0.5f*p[0]);
  float cy = cosf(0.5f*p[1]), syn = sinf(0.5f*p[1]);
  float cz = cosf(0.5f*p[2]), szn = sinf(0.5f*p[2]);
  Cf RX[4] = {{cx,0.f},{0.f,-sxn},{0.f,-sxn},{cx,0.f}};
  Cf RY[4] = {{cy,0.f},{-syn,0.f},{syn,0.f},{cy,0.f}};
  Cf RZ[4] = {{cz,-szn},{0.f,0.f},{0.f,0.f},{cz,szn}};
  Cf M[4];
  mm2(RY, RX, M);
  mm2(RZ, M, U);
}

__device__ __forceinline__ void rxmat(float th, Cf R[4]) {
  float c = cosf(0.5f*th), s = sinf(0.5f*th);
  R[0] = {c,0.f}; R[1] = {0.f,-s}; R[2] = {0.f,-s}; R[3] = {c,0.f};
}

template<int CTRL>
__device__ __forceinline__ float dppf(float v) {
  return __int_as_float(__builtin_amdgcn_mov_dpp(__float_as_int(v), CTRL, 0xF, 0xF, true));
}

// xor-lane exchange, ALL DPP: 1,2,3 quad_perm; 4 = half_mirror∘quad_rev;
// 8 = row_ror:8 (xor8 within 16-lane row)
template<int M>
__device__ __forceinline__ float sx(float v) {
  if constexpr (M == 1)      return dppf<0xB1>(v);
  else if constexpr (M == 2) return dppf<0x4E>(v);
  else if constexpr (M == 3) return dppf<0x1B>(v);
  else if constexpr (M == 4) return dppf<0x141>(dppf<0x1B>(v));
  else                       return dppf<0x128>(v);   // M == 8
}

// out = c0*v0 + c1*v1 + c2*v2 + c3*v3 (complex; coefs packed r,i pairs)
__device__ __forceinline__ float2 c4acc(float2 v0, float2 v1, float2 v2, float2 v3,
                                        float4 c01, float4 c23) {
  float ox = c01.x*v0.x - c01.y*v0.y + c01.z*v1.x - c01.w*v1.y
           + c23.x*v2.x - c23.y*v2.y + c23.z*v3.x - c23.w*v3.y;
  float oy = c01.x*v0.y + c01.y*v0.x + c01.z*v1.y + c01.w*v1.x
           + c23.x*v2.y + c23.y*v2.x + c23.z*v3.y + c23.w*v3.x;
  return {ox, oy};
}

// full 2x2 on the in-thread register pair (q0)
__device__ __forceinline__ void rgate(float2& A, float2& B, float4 r0, float4 r1) {
  float2 A0 = A, B0 = B;
  A.x = r0.x*A0.x - r0.y*A0.y + r0.z*B0.x - r0.w*B0.y;
  A.y = r0.x*A0.y + r0.y*A0.x + r0.z*B0.y + r0.w*B0.x;
  B.x = r1.x*A0.x - r1.y*A0.y + r1.z*B0.x - r1.w*B0.y;
  B.y = r1.x*A0.y + r1.y*A0.x + r1.z*B0.y + r1.w*B0.x;
}

__global__ __launch_bounds__(BLOCK)
void qrnn_kernel(const float* __restrict__ x, const float* __restrict__ hin,
                 const float* __restrict__ params, float* __restrict__ out) {
  const int b    = blockIdx.x;
  const int tid  = threadIdx.x;
  const int lane = tid & 63;
  const int w    = tid >> 6;

  if (w == 0) {
    // ================= hidden recurrence (single wave, all-DPP) ============
    const int l3 = (lane>>3)&1, l2 = (lane>>2)&1, l1 = (lane>>1)&1, l0 = lane&1;

    // ---- layer-1 fused 1q matrices (lane-uniform) ----
    Cf u1q[5][4];
    #pragma unroll
    for (int q = 0; q < 5; ++q) fusedU(params + 3*q, u1q[q]);
    // L1 CRX constants (folded into embed): (q0,q1) full; others ctrl-blended
    float c1f, s1f, cB2, sB2, cB3, sB3, cB4, sB4;
    { float t0 = params[15]; c1f = cosf(0.5f*t0); s1f = sinf(0.5f*t0); }
    { float t1 = params[16]; cB2 = l3 ? cosf(0.5f*t1) : 1.f; sB2 = l3 ? sinf(0.5f*t1) : 0.f; }
    { float t2 = params[17]; cB3 = l2 ? cosf(0.5f*t2) : 1.f; sB3 = l2 ? sinf(0.5f*t2) : 0.f; }
    { float t3 = params[18]; cB4 = l1 ? cosf(0.5f*t3) : 1.f; sB4 = l1 ? sinf(0.5f*t3) : 0.f; }

    // ---- L2 q0 gate (register 2x2) ----
    float4 Mq0r0, Mq0r1;
    { Cf U[4]; fusedU(params + 37, U);
      Mq0r0 = make_float4(U[0].r, U[0].i, U[1].r, U[1].i);
      Mq0r1 = make_float4(U[2].r, U[2].i, U[3].r, U[3].i); }

    // ---- L2 fused pass matrices: per-lane 4-term rows ----
    float4 cA0_01, cA0_23, cA1_01, cA1_23, cB_01, cB_23;
    {
      Cf U1[4], U2[4], U3[4], U4[4];
      fusedU(params + 40, U1);   // L2 q1
      fusedU(params + 43, U2);   // L2 q2
      fusedU(params + 46, U3);   // L2 q3
      fusedU(params + 49, U4);   // L2 q4
      Cf R1[4], R2[4], R3[4], R4[4];
      rxmat(params[52], R1);     // CRX01 rotation
      rxmat(params[53], R2);     // CRX12
      rxmat(params[54], R3);     // CRX23
      rxmat(params[55], R4);     // CRX34
      Cf K[4][4], T[4][4], M0[4][4], M1[4][4];
      // ---- pass A on (l3,l2): row bit1 = l3, bit0 = l2 ----
      #pragma unroll
      for (int i = 0; i < 4; ++i)
        #pragma unroll
        for (int j = 0; j < 4; ++j)
          K[i][j] = cmul(U1[(i>>1)*2 + (j>>1)], U2[(i&1)*2 + (j&1)]);
      // T = (RX1 on bit1) * K
      #pragma unroll
      for (int i = 0; i < 4; ++i)
        #pragma unroll
        for (int j = 0; j < 4; ++j)
          T[i][j] = cadd(cmul(R1[(i>>1)*2 + 0], K[(0<<1)|(i&1)][j]),
                         cmul(R1[(i>>1)*2 + 1], K[(1<<1)|(i&1)][j]));
      // M0 = C12*K ; M1 = C12*T   (C12: rows with bit1==1 get RX2 on bit0)
      #pragma unroll
      for (int i = 0; i < 4; ++i)
        #pragma unroll
        for (int j = 0; j < 4; ++j) {
          if ((i>>1) == 0) { M0[i][j] = K[i][j]; M1[i][j] = T[i][j]; }
          else {
            M0[i][j] = cadd(cmul(R2[(i&1)*2 + 0], K[2|0][j]),
                            cmul(R2[(i&1)*2 + 1], K[2|1][j]));
            M1[i][j] = cadd(cmul(R2[(i&1)*2 + 0], T[2|0][j]),
                            cmul(R2[(i&1)*2 + 1], T[2|1][j]));
          }
        }
      const int rowA = (l3<<1) | l2;
      cA0_01 = make_float4(M0[rowA][rowA^0].r, M0[rowA][rowA^0].i,
                           M0[rowA][rowA^1].r, M0[rowA][rowA^1].i);
      cA0_23 = make_float4(M0[rowA][rowA^2].r, M0[rowA][rowA^2].i,
                           M0[rowA][rowA^3].r, M0[rowA][rowA^3].i);
      cA1_01 = make_float4(M1[rowA][rowA^0].r, M1[rowA][rowA^0].i,
                           M1[rowA][rowA^1].r, M1[rowA][rowA^1].i);
      cA1_23 = make_float4(M1[rowA][rowA^2].r, M1[rowA][rowA^2].i,
                           M1[rowA][rowA^3].r, M1[rowA][rowA^3].i);
      // ---- pass B on (l1,l0): row bit1 = l1, bit0 = l0; l2 blends RX3 ----
      #pragma unroll
      for (int i = 0; i < 4; ++i)
        #pragma unroll
        for (int j = 0; j < 4; ++j)
          K[i][j] = cmul(U3[(i>>1)*2 + (j>>1)], U4[(i&1)*2 + (j&1)]);
      #pragma unroll
      for (int i = 0; i < 4; ++i)
        #pragma unroll
        for (int j = 0; j < 4; ++j)
          T[i][j] = l2 ? cadd(cmul(R3[(i>>1)*2 + 0], K[(0<<1)|(i&1)][j]),
                              cmul(R3[(i>>1)*2 + 1], K[(1<<1)|(i&1)][j]))
                       : K[i][j];
      #pragma unroll
      for (int i = 0; i < 4; ++i)
        #pragma unroll
        for (int j = 0; j < 4; ++j)
          M0[i][j] = ((i>>1) == 0) ? T[i][j]
                   : cadd(cmul(R4[(i&1)*2 + 0], T[2|0][j]),
                          cmul(R4[(i&1)*2 + 1], T[2|1][j]));
      const int rowB = (l1<<1) | l0;
      cB_01 = make_float4(M0[rowB][rowB^0].r, M0[rowB][rowB^0].i,
                          M0[rowB][rowB^1].r, M0[rowB][rowB^1].i);
      cB_23 = make_float4(M0[rowB][rowB^2].r, M0[rowB][rowB^2].i,
                          M0[rowB][rowB^3].r, M0[rowB][rowB^3].i);
    }

    // hidden state stored as HALF-angles
    const float* hp = hin + b*5;
    float h0 = 0.5f*hp[0], h1 = 0.5f*hp[1], h2 = 0.5f*hp[2],
          h3 = 0.5f*hp[3], h4 = 0.5f*hp[4];

    #pragma unroll 1
    for (int t = 0; t < TSTEPS; ++t) {
      float cc0 = __cosf(h0), ss0 = __sinf(h0);
      float cc1 = __cosf(h1), ss1 = __sinf(h1);
      float cc2 = __cosf(h2), ss2 = __sinf(h2);
      float cc3 = __cosf(h3), ss3 = __sinf(h3);
      float cc4 = __cosf(h4), ss4 = __sinf(h4);
      // e_q = U1q * (cos, -i sin): both components
      Cf e0a{u1q[0][0].r*cc0 + u1q[0][1].i*ss0, u1q[0][0].i*cc0 - u1q[0][1].r*ss0};
      Cf e0b{u1q[0][2].r*cc0 + u1q[0][3].i*ss0, u1q[0][2].i*cc0 - u1q[0][3].r*ss0};
      Cf e1a{u1q[1][0].r*cc1 + u1q[1][1].i*ss1, u1q[1][0].i*cc1 - u1q[1][1].r*ss1};
      Cf e1b{u1q[1][2].r*cc1 + u1q[1][3].i*ss1, u1q[1][2].i*cc1 - u1q[1][3].r*ss1};
      Cf e2a{u1q[2][0].r*cc2 + u1q[2][1].i*ss2, u1q[2][0].i*cc2 - u1q[2][1].r*ss2};
      Cf e2b{u1q[2][2].r*cc2 + u1q[2][3].i*ss2, u1q[2][2].i*cc2 - u1q[2][3].r*ss2};
      Cf e3a{u1q[3][0].r*cc3 + u1q[3][1].i*ss3, u1q[3][0].i*cc3 - u1q[3][1].r*ss3};
      Cf e3b{u1q[3][2].r*cc3 + u1q[3][3].i*ss3, u1q[3][2].i*cc3 - u1q[3][3].r*ss3};
      Cf e4a{u1q[4][0].r*cc4 + u1q[4][1].i*ss4, u1q[4][0].i*cc4 - u1q[4][1].r*ss4};
      Cf e4b{u1q[4][2].r*cc4 + u1q[4][3].i*ss4, u1q[4][2].i*cc4 - u1q[4][3].r*ss4};

      // per-lane row selects + L1-CRX folds (verified R9)
      Cf E1s = l3 ? e1b : e1a, E1x = l3 ? e1a : e1b;
      Cf G0  = E1s;
      Cf G1  {c1f*E1s.r + s1f*E1x.i, c1f*E1s.i - s1f*E1x.r};
      Cf E2s = l2 ? e2b : e2a, E2x = l2 ? e2a : e2b;
      Cf E2  {cB2*E2s.r + sB2*E2x.i, cB2*E2s.i - sB2*E2x.r};
      Cf E3s = l1 ? e3b : e3a, E3x = l1 ? e3a : e3b;
      Cf E3  {cB3*E3s.r + sB3*E3x.i, cB3*E3s.i - sB3*E3x.r};
      Cf E4s = l0 ? e4b : e4a, E4x = l0 ? e4a : e4b;
      Cf E4  {cB4*E4s.r + sB4*E4x.i, cB4*E4s.i - sB4*E4x.r};

      Cf C  = cmul(E2, cmul(E3, E4));
      Cf A0 = cmul(cmul(e0a, G0), C);
      Cf A1 = cmul(cmul(e0b, G1), C);
      float2 a0{A0.r, A0.i}, a1{A1.r, A1.i};

      // ---- layer 2: THREE passes ----
      rgate(a0, a1, Mq0r0, Mq0r1);
      // pass A: (l3,l2) fused 4x4 (exchanges xor4, xor8, xor12=xor8∘xor4)
      {
        float a0x4 = sx<4>(a0.x), a0y4 = sx<4>(a0.y);
        float a1x4 = sx<4>(a1.x), a1y4 = sx<4>(a1.y);
        float a0x8 = sx<8>(a0.x), a0y8 = sx<8>(a0.y);
        float a1x8 = sx<8>(a1.x), a1y8 = sx<8>(a1.y);
        float a0xC = sx<8>(a0x4), a0yC = sx<8>(a0y4);
        float a1xC = sx<8>(a1x4), a1yC = sx<8>(a1y4);
        float2 n0 = c4acc(a0, {a0x4,a0y4}, {a0x8,a0y8}, {a0xC,a0yC}, cA0_01, cA0_23);
        float2 n1 = c4acc(a1, {a1x4,a1y4}, {a1x8,a1y8}, {a1xC,a1yC}, cA1_01, cA1_23);
        a0 = n0; a1 = n1;
      }
      // pass B: (l1,l0) fused 4x4 (single quad_perm per mask)
      {
        float a0x1 = sx<1>(a0.x), a0y1 = sx<1>(a0.y);
        float a1x1 = sx<1>(a1.x), a1y1 = sx<1>(a1.y);
        float a0x2 = sx<2>(a0.x), a0y2 = sx<2>(a0.y);
        float a1x2 = sx<2>(a1.x), a1y2 = sx<2>(a1.y);
        float a0x3 = sx<3>(a0.x), a0y3 = sx<3>(a0.y);
        float a1x3 = sx<3>(a1.x), a1y3 = sx<3>(a1.y);
        float2 n0 = c4acc(a0, {a0x1,a0y1}, {a0x2,a0y2}, {a0x3,a0y3}, cB_01, cB_23);
        float2 n1 = c4acc(a1, {a1x1,a1y1}, {a1x2,a1y2}, {a1x3,a1y3}, cB_01, cB_23);
        a0 = n0; a1 = n1;
      }

      // measurement, scaled by 0.5 (next step consumes half-angles)
      float p0 = (0.5f*a0.x)*a0.x + (0.5f*a0.y)*a0.y;
      float p1 = (0.5f*a1.x)*a1.x + (0.5f*a1.y)*a1.y;
      float S = p0 + p1, D = p0 - p1;
      float T1, T2, T4, T8;
      { float xx = sx<1>(S); T1 = (lane&1) ? xx-S : S-xx; S += xx; D += sx<1>(D); }
      { float xx = sx<2>(S); T2 = (lane&2) ? xx-S : S-xx; S += xx; D += sx<2>(D);
        T1 += sx<2>(T1); }
      { float xx = sx<4>(S); T4 = (lane&4) ? xx-S : S-xx; S += xx; D += sx<4>(D);
        T1 += sx<4>(T1); T2 += sx<4>(T2); }
      { float xx = sx<8>(S); T8 = (lane&8) ? xx-S : S-xx; S += xx; D += sx<8>(D);
        T1 += sx<8>(T1); T2 += sx<8>(T2); T4 += sx<8>(T4); }
      h0 = D; h1 = T8; h2 = T4; h3 = T2; h4 = T1;
    }
    if (lane < 5) {
      float hv = (lane==0) ? h0 : (lane==1) ? h1 : (lane==2) ? h2
               : (lane==3) ? h3 : h4;
      out[BATCH*TSTEPS*6 + b*5 + lane] = 2.f*hv;    // un-halve
    }
  } else if (w == 1) {
    // ================= visible outputs (no recurrence) =====================
    const int t = lane;
    if (t < TSTEPS) {
      const float* xp = x + (size_t)b*(TSTEPS*FEAT) + t*FEAT;
      float pooled[6];
      #pragma unroll
      for (int k = 0; k < 6; ++k) {
        float s = 0.f;
        #pragma unroll
        for (int f = 0; f < 10; ++f) s += xp[k*10 + f];
        pooled[k] = s * 0.1f;
      }
      float mn = pooled[0], mx = pooled[0];
      #pragma unroll
      for (int v = 1; v < 6; ++v) {
        mn = fminf(mn, pooled[v]); mx = fmaxf(mx, pooled[v]);
      }
      float* op = out + (size_t)b*(TSTEPS*6) + t*6;
      #pragma unroll
      for (int k = 0; k < 6; ++k) {
        Cf U1[4], U2[4], W[4];
        fusedU(params + 19 + 3*k, U1);       // layer 1, visible qubit k
        fusedU(params + 56 + 3*k, U2);       // layer 2, visible qubit k
        mm2(U2, U1, W);                      // W = U2*U1
        float ang = TWO_PI_F * (pooled[k] - mn) / (mx - mn + 1e-8f);
        float ch = __cosf(0.5f*ang), sh = __sinf(0.5f*ang);
        float v0r = W[0].r*ch + W[1].i*sh, v0i = W[0].i*ch - W[1].r*sh;
        float v1r = W[2].r*ch + W[3].i*sh, v1i = W[2].i*ch - W[3].r*sh;
        op[k] = (v0r*v0r + v0i*v0i) - (v1r*v1r + v1i*v1i);
      }
    }
  }
}

extern "C" void kernel_launch(void* const* d_in, const int* in_sizes, int n_in,
                              void* d_out, int out_size, void* d_ws, size_t ws_size,
                              hipStream_t stream) {
  const float* x      = (const float*)d_in[0];
  const float* hidden = (const float*)d_in[1];
  const float* params = (const float*)d_in[2];
  float* out          = (float*)d_out;
  qrnn_kernel<<<dim3(BATCH), dim3(BLOCK), 0, stream>>>(x, hidden, params, out);
}